// Round 1
// baseline (436.865 us; speedup 1.0000x reference)
//
#include <hip/hip_runtime.h>

typedef short s16x8 __attribute__((ext_vector_type(8)));
typedef float f32x4 __attribute__((ext_vector_type(4)));

#define BDIM 512
#define XSTR 6144      // S*I floats per batch row
#define XCS  388       // padded col stride in xbuf (floats): 32*12+4

// LDS byte offsets
#define OFF_G   0                  // bufG[2 dbuf][2 chunk][1024]
#define OFF_A   4096               // bufA[2 chunk][1024]
#define OFF_L1  6144               // l1 frag buffer (1024)
#define OFF_W   7168               // softmax weights, 16 f32
#define OFF_VL  7232               // v_last fp32, 64 f32
#define OFF_FF  7488               // feat for final MLP, 8*40 f32
#define OFF_R1  8768               // r1 buffer, 8*32 f32
#define ZERO_WORDS (9792/4)
#define OFF_WE  9792               // We 96 f32
#define OFF_BE  (9792 + 96*4)      // be 8 f32
#define OFF_X   10208              // xbuf[2][8][XCS] f32
#define LDS_SZ  (10208 + 2*8*XCS*4)

__device__ __forceinline__ short f2bf(float f) {
  union { float f; unsigned u; } v; v.f = f;
  unsigned r = v.u + 0x7fffu + ((v.u >> 16) & 1u);
  return (short)(r >> 16);
}
__device__ __forceinline__ float sigf(float x) {
  return __builtin_amdgcn_rcpf(1.f + __expf(-x));
}
__device__ __forceinline__ float tanh_f(float x) {
  return 1.f - 2.f * __builtin_amdgcn_rcpf(__expf(2.f * x) + 1.f);
}
__device__ __forceinline__ float lrelu_f(float x) {
  return x > 0.f ? x : 0.01f * x;
}

__global__ __launch_bounds__(BDIM, 4) void arnn_kernel(
    const float* __restrict__ X,   const float* __restrict__ We,  const float* __restrict__ be,
    const float* __restrict__ W_ih,const float* __restrict__ W_hh,
    const float* __restrict__ b_ih,const float* __restrict__ b_hh,
    const float* __restrict__ Ew1, const float* __restrict__ Eb1,
    const float* __restrict__ Ew2, const float* __restrict__ Eb2,
    const float* __restrict__ Ew3, const float* __restrict__ Eb3,
    const float* __restrict__ Rw1, const float* __restrict__ Rb1,
    const float* __restrict__ Rw2, const float* __restrict__ Rb2,
    const float* __restrict__ Rw3, const float* __restrict__ Rb3,
    float* __restrict__ out)
{
  __shared__ __align__(16) char lds[LDS_SZ];
  const int tid  = threadIdx.x;
  const int wv   = tid >> 6;     // wave 0..7 : owns gate rows [16*wv, 16*wv+16)
  const int lane = tid & 63;
  const int q    = lane >> 4;
  const int r    = lane & 15;    // batch col (0..7 valid)
  const int blk  = blockIdx.x;

  // zero control LDS (bufG/bufA/bufL1/wbuf must start zero)
  for (int i = tid; i < ZERO_WORDS; i += BDIM) ((int*)lds)[i] = 0;
  // stage We/be to LDS (outside zeroed range)
  if (tid < 96) ((float*)(lds + OFF_WE))[tid] = We[tid];
  if (tid < 8)  ((float*)(lds + OFF_BE))[tid] = be[tid];

  // ---- gate A-fragments: interleaved row R=16wv+r -> unit u=R>>2, comp c=R&3,
  //      original weight row = 32c + u.  K layout: k0..7=v_t, k8..39=h, rest 0.
  s16x8 ag0, ag1;
  {
    const int R = wv*16 + r;
    const int orow = (R & 3)*32 + (R >> 2);
#pragma unroll
    for (int j = 0; j < 8; ++j) {
      const int k0 = q*8 + j;
      ag0[j] = f2bf(k0 < 8 ? W_ih[orow*8 + k0] : W_hh[orow*32 + (k0-8)]);
      const int k1 = 32 + k0;
      ag1[j] = f2bf(k1 < 40 ? W_hh[orow*32 + (k1-8)] : 0.f);
    }
  }
  const int u = wv*4 + q;                 // hidden unit owned by this lane
  const float bias0 = b_ih[u]    + b_hh[u];
  const float bias1 = b_ih[32+u] + b_hh[32+u];
  const float bias2 = b_ih[64+u] + b_hh[64+u];
  const float bias3 = b_ih[96+u] + b_hh[96+u];

  // h scatter address inside a B-frag buffer: k = 8+u
  const int hk = 8 + u;
  const int haddr = (hk >> 5)*1024 + ((((hk & 31) >> 3) << 4) | r)*16 + ((hk & 31) & 7)*2;

  // ---- attention fragments (wave 7 only) ----
  s16x8 e1c0 = {}, e1c1 = {}, e2t0 = {}, e2t1 = {};
  f32x4 eb1v = {};
  float eb2r[8], ew3r[8], eb3s = 0.f;
  if (wv == 7) {
    const int o = r;  // l1 output index
#pragma unroll
    for (int j = 0; j < 8; ++j) {
      const int k0 = q*8 + j;
      e1c0[j] = f2bf(k0 < 8 ? Ew1[(32+k0)*16 + o] : Ew1[(k0-8)*16 + o]);
      const int k1 = 32 + k0;
      e1c1[j] = f2bf(k1 < 40 ? Ew1[(k1-8)*16 + o] : 0.f);
      e2t0[j] = f2bf(k0 < 16 ? Ew2[k0*32 + o] : 0.f);
      e2t1[j] = f2bf(k0 < 16 ? Ew2[k0*32 + 16 + o] : 0.f);
    }
#pragma unroll
    for (int t = 0; t < 4; ++t) {
      eb1v[t]   = Eb1[q*4 + t];
      eb2r[t]   = Eb2[q*4 + t];
      eb2r[4+t] = Eb2[16 + q*4 + t];
      ew3r[t]   = Ew3[q*4 + t];
      ew3r[4+t] = Ew3[16 + q*4 + t];
    }
    eb3s = Eb3[0];
  }

  const int vcol = lane >> 3, ve = lane & 7;

  __syncthreads();   // zeros + We staged

  // prologue: x chunk 0 -> xbuf[0]
  {
    const float* xb = X + (long)blk*8*XSTR;
#pragma unroll
    for (int j = 0; j < 6; ++j) {
      const int idx = tid + j*BDIM;
      const int col = idx / 384, rem = idx - col*384;
      ((float*)(lds + OFF_X))[col*XCS + rem] = xb[(long)col*XSTR + rem];
    }
  }
  // v_last by wave 0 (reads x[...,511,:] directly)
  if (wv == 0) {
    const float* xl = X + (long)(blk*8 + vcol)*XSTR + 511*12;
    const float* WeL = (const float*)(lds + OFF_WE);
    float a = ((const float*)(lds + OFF_BE))[ve];
#pragma unroll
    for (int i = 0; i < 12; ++i) a = fmaf(xl[i], WeL[i*8 + ve], a);
    const float vl = lrelu_f(a);
    *(short*)(lds + OFF_A + vcol*16 + ve*2) = f2bf(vl);   // bufA rows k=0..7
    ((float*)(lds + OFF_VL))[vcol*8 + ve] = vl;
  }
  __syncthreads();   // xbuf0 + v_last visible

  // v(0) by wave 1 -> bufG[0] rows k=0..7
  if (wv == 1) {
    const float* xb = (const float*)(lds + OFF_X) + vcol*XCS;
    const float* WeL = (const float*)(lds + OFF_WE);
    float a = ((const float*)(lds + OFF_BE))[ve];
#pragma unroll
    for (int i = 0; i < 12; ++i) a = fmaf(xb[i], WeL[i*8 + ve], a);
    *(short*)(lds + OFF_G + vcol*16 + ve*2) = f2bf(lrelu_f(a));
  }
  __syncthreads();

  float c_state = 0.f, h_prev = 0.f, h_new = 0.f, accv = 0.f, lsum = 0.f;

  auto do_att = [&]() {  // attention MLP on bufA (h of previous phase) -> wbuf
    const s16x8 a0 = *(const s16x8*)(lds + OFF_A + lane*16);
    const s16x8 a1 = *(const s16x8*)(lds + OFF_A + 1024 + lane*16);
    f32x4 C1 = eb1v;
    C1 = __builtin_amdgcn_mfma_f32_16x16x32_bf16(e1c0, a0, C1, 0, 0, 0);
    C1 = __builtin_amdgcn_mfma_f32_16x16x32_bf16(e1c1, a1, C1, 0, 0, 0);
#pragma unroll
    for (int t = 0; t < 4; ++t) {
      const int o = q*4 + t;
      *(short*)(lds + OFF_L1 + (((o >> 3) << 4) | r)*16 + (o & 7)*2) = f2bf(lrelu_f(C1[t]));
    }
    const s16x8 bl = *(const s16x8*)(lds + OFF_L1 + lane*16);
    f32x4 C2a = {eb2r[0], eb2r[1], eb2r[2], eb2r[3]};
    f32x4 C2b = {eb2r[4], eb2r[5], eb2r[6], eb2r[7]};
    C2a = __builtin_amdgcn_mfma_f32_16x16x32_bf16(e2t0, bl, C2a, 0, 0, 0);
    C2b = __builtin_amdgcn_mfma_f32_16x16x32_bf16(e2t1, bl, C2b, 0, 0, 0);
    float part = 0.f;
#pragma unroll
    for (int t = 0; t < 4; ++t)
      part += lrelu_f(C2a[t])*ew3r[t] + lrelu_f(C2b[t])*ew3r[4+t];
    part += __shfl_xor(part, 16);
    part += __shfl_xor(part, 32);
    const float wgt = __expf(tanh_f(part + eb3s));  // logit in [-1,1]: exp safe
    if (lane < 16) ((float*)(lds + OFF_W))[lane] = wgt;
  };

  for (int s = 0; s < 512; ++s) {
    const int p = s & 1;
    // ---- phase A: gates MFMA + LSTM elementwise (+ deferred attention) ----
    const s16x8 bg0 = *(const s16x8*)(lds + OFF_G + p*2048 + lane*16);
    const s16x8 bg1 = *(const s16x8*)(lds + OFF_G + p*2048 + 1024 + lane*16);
    f32x4 C = {bias0, bias1, bias2, bias3};
    C = __builtin_amdgcn_mfma_f32_16x16x32_bf16(ag0, bg0, C, 0, 0, 0);
    C = __builtin_amdgcn_mfma_f32_16x16x32_bf16(ag1, bg1, C, 0, 0, 0);
    const float cn = sigf(C[1])*c_state + sigf(C[0])*tanh_f(C[2]);
    h_new = sigf(C[3])*tanh_f(cn);
    c_state = cn;
    if (wv == 7 && s > 0) do_att();   // computes w(s-1); wbuf starts zeroed
    __syncthreads();

    // ---- phase B: softmax-accumulate w(s-1), publish h(s), v(s+1), refills ----
    const float wgt = ((const float*)(lds + OFF_W))[r];
    accv = fmaf(wgt, h_prev, accv);
    lsum += wgt;
    const short hb = f2bf(h_new);
    *(short*)(lds + OFF_G + (p^1)*2048 + haddr) = hb;
    *(short*)(lds + OFF_A + haddr) = hb;
    h_prev = h_new;
    if (wv == 1 && s < 511) {   // embed v(s+1)
      const int sn = s + 1;
      const float* xb = (const float*)(lds + OFF_X) + ((sn >> 5) & 1)*(8*XCS)
                        + vcol*XCS + (sn & 31)*12;
      const float* WeL = (const float*)(lds + OFF_WE);
      float a = ((const float*)(lds + OFF_BE))[ve];
#pragma unroll
      for (int i = 0; i < 12; ++i) a = fmaf(xb[i], WeL[i*8 + ve], a);
      *(short*)(lds + OFF_G + (p^1)*2048 + vcol*16 + ve*2) = f2bf(lrelu_f(a));
    }
    if ((s & 31) == 0) {        // refill next x chunk (double buffered)
      const int ch = (s >> 5) + 1;
      if (ch < 16) {
        const float* xb = X + (long)blk*8*XSTR + ch*384;
        float* xw = (float*)(lds + OFF_X) + (ch & 1)*(8*XCS);
#pragma unroll
        for (int j = 0; j < 6; ++j) {
          const int idx = tid + j*BDIM;
          const int col = idx / 384, rem = idx - col*384;
          xw[col*XCS + rem] = xb[(long)col*XSTR + rem];
        }
      }
    }
    __syncthreads();
  }

  // attention for the last step, then final accumulate
  if (wv == 7) do_att();
  __syncthreads();
  {
    const float wgt = ((const float*)(lds + OFF_W))[r];
    accv = fmaf(wgt, h_prev, accv);
    lsum += wgt;
  }
  if (r < 8) ((float*)(lds + OFF_FF))[r*40 + u] = accv / lsum;        // h_final
  if (wv == 0)
    ((float*)(lds + OFF_FF))[vcol*40 + 32 + ve] = ((const float*)(lds + OFF_VL))[vcol*8 + ve];
  __syncthreads();

  // final MLP: wave wv handles batch col wv
  {
    const float* ff = (const float*)(lds + OFF_FF) + wv*40;
    if (lane < 32) {
      float a = Rb1[lane];
      for (int f = 0; f < 40; ++f) a = fmaf(ff[f], Rw1[f*32 + lane], a);
      ((float*)(lds + OFF_R1))[wv*32 + lane] = lrelu_f(a);
    }
    const float* r1b = (const float*)(lds + OFF_R1) + wv*32;
    float a2 = Rb2[lane];
    for (int pp = 0; pp < 32; ++pp) a2 = fmaf(r1b[pp], Rw2[pp*64 + lane], a2);
    a2 = lrelu_f(a2);
    float part = a2 * Rw3[lane];
#pragma unroll
    for (int m = 1; m < 64; m <<= 1) part += __shfl_xor(part, m);
    if (lane == 0) out[blk*8 + wv] = sigf(part + Rb3[0]);
  }
}

extern "C" void kernel_launch(void* const* d_in, const int* in_sizes, int n_in,
                              void* d_out, int out_size, void* d_ws, size_t ws_size,
                              hipStream_t stream) {
  const float* X    = (const float*)d_in[0];
  const float* We   = (const float*)d_in[1];
  const float* be   = (const float*)d_in[2];
  const float* W_ih = (const float*)d_in[3];
  const float* W_hh = (const float*)d_in[4];
  const float* b_ih = (const float*)d_in[5];
  const float* b_hh = (const float*)d_in[6];
  const float* Ew1  = (const float*)d_in[7];
  const float* Eb1  = (const float*)d_in[8];
  const float* Ew2  = (const float*)d_in[9];
  const float* Eb2  = (const float*)d_in[10];
  const float* Ew3  = (const float*)d_in[11];
  const float* Eb3  = (const float*)d_in[12];
  const float* Rw1  = (const float*)d_in[13];
  const float* Rb1  = (const float*)d_in[14];
  const float* Rw2  = (const float*)d_in[15];
  const float* Rb2  = (const float*)d_in[16];
  const float* Rw3  = (const float*)d_in[17];
  const float* Rb3  = (const float*)d_in[18];

  arnn_kernel<<<dim3(512), dim3(BDIM), 0, stream>>>(
      X, We, be, W_ih, W_hh, b_ih, b_hh,
      Ew1, Eb1, Ew2, Eb2, Ew3, Eb3,
      Rw1, Rb1, Rw2, Rb2, Rw3, Rb3,
      (float*)d_out);
}

// Round 2
// 349.990 us; speedup vs baseline: 1.2482x; 1.2482x over previous
//
#include <hip/hip_runtime.h>

typedef short s16x8 __attribute__((ext_vector_type(8)));
typedef float f32x4 __attribute__((ext_vector_type(4)));
typedef unsigned int u32x4 __attribute__((ext_vector_type(4)));

// ---- LDS offsets (kernel 2) ----
#define OFF_HEX 0      // h exchange: 2 dbuf * 16 cols * 4 q * 8 units * 2B = 2048
#define OFF_WGT 2048   // softmax weights: 2 dbuf * 16 f32 = 128
#define OFF_FF  2176   // final features: 16 * 40 * 4 = 2560
#define OFF_R1  4736   // head hidden: 8 waves * 32 * 4 = 1024
#define LDS2    5760

__device__ __forceinline__ short f2bf(float f) {
  union { float f; unsigned u; } v; v.f = f;
  unsigned r = v.u + 0x7fffu + ((v.u >> 16) & 1u);
  return (short)(r >> 16);
}
__device__ __forceinline__ float sigf(float x)   { return __builtin_amdgcn_rcpf(1.f + __expf(-x)); }
__device__ __forceinline__ float tanh_f(float x) { return 1.f - 2.f * __builtin_amdgcn_rcpf(__expf(2.f * x) + 1.f); }
__device__ __forceinline__ float lrelu_f(float x){ return x > 0.f ? x : 0.01f * x; }
__device__ __forceinline__ int   pk2(short a, short b){ return (int)((unsigned short)a) | ((int)((unsigned short)b) << 16); }

// ===================== kernel 1: embed v = lrelu(x@We+be) =====================
// V layout: [b][s][e] bf16 (16B per (b,s)); VLAST: [b][e] fp32
__global__ __launch_bounds__(256) void embed_kernel(
    const float* __restrict__ X, const float* __restrict__ We, const float* __restrict__ be,
    unsigned short* __restrict__ V, float* __restrict__ VLAST)
{
  __shared__ float sWe[96];
  __shared__ float sbe[8];
  const int tid = threadIdx.x;
  if (tid < 96) sWe[tid] = We[tid];
  if (tid < 8)  sbe[tid] = be[tid];
  __syncthreads();

  const long gid = (long)blockIdx.x * 256 + tid;   // gid = b*512 + s
  const float* xp = X + gid * 12;
  float xr[12];
  *(float4*)&xr[0] = *(const float4*)(xp);
  *(float4*)&xr[4] = *(const float4*)(xp + 4);
  *(float4*)&xr[8] = *(const float4*)(xp + 8);

  float v[8];
#pragma unroll
  for (int e = 0; e < 8; ++e) {
    float a = sbe[e];
#pragma unroll
    for (int i = 0; i < 12; ++i) a = fmaf(xr[i], sWe[i*8 + e], a);
    v[e] = lrelu_f(a);
  }
  unsigned int pkv[4];
#pragma unroll
  for (int d = 0; d < 4; ++d)
    pkv[d] = (unsigned)pk2(f2bf(v[2*d]), f2bf(v[2*d+1]));
  *(u32x4*)(V + gid * 8) = *(u32x4*)pkv;

  if ((gid & 511) == 511) {
    const long b = gid >> 9;
#pragma unroll
    for (int e = 0; e < 8; ++e) VLAST[b*8 + e] = v[e];
  }
}

// ===================== kernel 2: fused LSTM + attention + head =====================
__global__ __launch_bounds__(512, 1) void arnn_kernel(
    const unsigned short* __restrict__ V, const float* __restrict__ VLAST,
    const float* __restrict__ W_ih, const float* __restrict__ W_hh,
    const float* __restrict__ b_ih, const float* __restrict__ b_hh,
    const float* __restrict__ Ew1, const float* __restrict__ Eb1,
    const float* __restrict__ Ew2, const float* __restrict__ Eb2,
    const float* __restrict__ Ew3, const float* __restrict__ Eb3,
    const float* __restrict__ Rw1, const float* __restrict__ Rb1,
    const float* __restrict__ Rw2, const float* __restrict__ Rb2,
    const float* __restrict__ Rw3, const float* __restrict__ Rb3,
    float* __restrict__ out)
{
  __shared__ __align__(16) char lds[LDS2];
  const int tid = threadIdx.x;
  const int wv = tid >> 6;        // wave = gate M-tile index m
  const int lane = tid & 63;
  const int q = lane >> 4;
  const int n = lane & 15;        // batch column within block
  const int blk = blockIdx.x;

  // zero HEX (2048B) + WGT (128B)
  if (tid < 544) ((int*)lds)[tid] = 0;

  // ---- gate A-fragments: tile wv, row R16 = lane&15 ----
  // global gate row R = wv*16+R16 -> unit u = ((R16>>2)&3)*8 + wv, comp c = R16&3
  // K layout: k0..31 = h[k], k32..39 = v_t[k-32]
  s16x8 a0, a1;
  {
    const int c = n & 3;
    const int uu = ((n >> 2) & 3) * 8 + wv;
    const int orow = c * 32 + uu;
#pragma unroll
    for (int j = 0; j < 8; ++j) {
      a0[j] = f2bf(W_hh[orow*32 + q*8 + j]);
      a1[j] = (q == 0) ? f2bf(W_ih[orow*8 + j]) : (short)0;
    }
  }
  const int u_own = q*8 + wv;     // unit whose (i,f,g,o) this lane computes
  float bias[4];
#pragma unroll
  for (int t = 0; t < 4; ++t) bias[t] = b_ih[t*32 + u_own] + b_hh[t*32 + u_own];

  // ---- attention fragments (wave 7 only) ----
  s16x8 e1a0 = {}, e1a1 = {}, e2t0 = {}, e2t1 = {};
  f32x4 eb1v = {};
  float eb2r[8] = {0,0,0,0,0,0,0,0}, ew3r[8] = {0,0,0,0,0,0,0,0}, eb3s = 0.f;
  u32x4 vlf = {0,0,0,0};
  if (wv == 7) {
#pragma unroll
    for (int j = 0; j < 8; ++j) {
      const int k = q*8 + j;
      e1a0[j] = f2bf(Ew1[k*16 + n]);                                  // feat rows 0..31 = h
      e1a1[j] = (q == 0) ? f2bf(Ew1[(32 + j)*16 + n]) : (short)0;     // rows 32..39 = v_last
      e2t0[j] = (k < 16) ? f2bf(Ew2[k*32 + n])      : (short)0;
      e2t1[j] = (k < 16) ? f2bf(Ew2[k*32 + 16 + n]) : (short)0;
    }
#pragma unroll
    for (int t = 0; t < 4; ++t) {
      eb1v[t]   = Eb1[q*4 + t];
      eb2r[t]   = Eb2[q*4 + t];
      eb2r[4+t] = Eb2[16 + q*4 + t];
      ew3r[t]   = Ew3[q*4 + t];
      ew3r[4+t] = Ew3[16 + q*4 + t];
    }
    eb3s = Eb3[0];
    if (q == 0) vlf = *(const u32x4*)(V + ((long)(blk*16 + n)*512 + 511)*8);
  }

  // attention MLP: h(prev) B-frag + v_last frag -> wgt, written to WGT[wbuf]
  auto do_att = [&](const s16x8& bh, int wbuf) {
    f32x4 C1 = eb1v;
    C1 = __builtin_amdgcn_mfma_f32_16x16x32_bf16(e1a0, bh, C1, 0, 0, 0);
    C1 = __builtin_amdgcn_mfma_f32_16x16x32_bf16(e1a1, *(const s16x8*)&vlf, C1, 0, 0, 0);
    const int d0 = pk2(f2bf(lrelu_f(C1[0])), f2bf(lrelu_f(C1[1])));
    const int d1 = pk2(f2bf(lrelu_f(C1[2])), f2bf(lrelu_f(C1[3])));
    // l1 rows q*4+t -> B-frag rows q*8+j (valid k<16 i.e. q<2)
    const int L1 = (((2*q) & 3)*16 + n) * 4;
    const int L2 = (((2*q + 1) & 3)*16 + n) * 4;
    const int w0 = __builtin_amdgcn_ds_bpermute(L1, d0);
    const int w1 = __builtin_amdgcn_ds_bpermute(L1, d1);
    const int w2 = __builtin_amdgcn_ds_bpermute(L2, d0);
    const int w3 = __builtin_amdgcn_ds_bpermute(L2, d1);
    int bw[4];
    const bool val = (q < 2);
    bw[0] = val ? w0 : 0; bw[1] = val ? w1 : 0; bw[2] = val ? w2 : 0; bw[3] = val ? w3 : 0;
    const s16x8 bl = *(const s16x8*)bw;
    f32x4 C2a = {eb2r[0], eb2r[1], eb2r[2], eb2r[3]};
    f32x4 C2b = {eb2r[4], eb2r[5], eb2r[6], eb2r[7]};
    C2a = __builtin_amdgcn_mfma_f32_16x16x32_bf16(e2t0, bl, C2a, 0, 0, 0);
    C2b = __builtin_amdgcn_mfma_f32_16x16x32_bf16(e2t1, bl, C2b, 0, 0, 0);
    float part = 0.f;
#pragma unroll
    for (int t = 0; t < 4; ++t)
      part += lrelu_f(C2a[t])*ew3r[t] + lrelu_f(C2b[t])*ew3r[4+t];
    part += __shfl_xor(part, 16);
    part += __shfl_xor(part, 32);
    const float wgt = __expf(tanh_f(part + eb3s));   // logit in [-1,1]
    if (lane < 16) ((float*)(lds + OFF_WGT))[wbuf*16 + lane] = wgt;
  };

  // ---- v_t prefetch pipeline (depth 2), all 4 q-lanes load same 16B (broadcast) ----
  const unsigned short* vbase = V + (long)(blk*16 + n)*512*8;
  u32x4 vpA = *(const u32x4*)(vbase);
  u32x4 vpB = *(const u32x4*)(vbase + 8);

  float c_state = 0.f, hm1 = 0.f, hm2 = 0.f, accv = 0.f, lsum = 0.f;
  __syncthreads();

  for (int s = 0; s < 512; ++s) {
    const int db = s & 1;
    const s16x8 bh = *(const s16x8*)(lds + OFF_HEX + db*1024 + (n*4 + q)*16);   // h(s-1)
    const float wprev = ((const float*)(lds + OFF_WGT))[db*16 + n];             // wgt(s-2)

    const u32x4 vz = {0,0,0,0};
    u32x4 vsel = (q == 0) ? vpA : vz;
    const s16x8 b1 = *(const s16x8*)&vsel;

    f32x4 C = {bias[0], bias[1], bias[2], bias[3]};
    C = __builtin_amdgcn_mfma_f32_16x16x32_bf16(a0, bh, C, 0, 0, 0);
    C = __builtin_amdgcn_mfma_f32_16x16x32_bf16(a1, b1, C, 0, 0, 0);

    vpA = vpB;
    { const int sp = (s + 2 < 512) ? s + 2 : 511; vpB = *(const u32x4*)(vbase + sp*8); }

    if (s >= 2) { accv = fmaf(wprev, hm2, accv); lsum += wprev; }

    const float cn = sigf(C[1])*c_state + sigf(C[0])*tanh_f(C[2]);
    const float hn = sigf(C[3])*tanh_f(cn);
    c_state = cn; hm2 = hm1; hm1 = hn;
    *(short*)(lds + OFF_HEX + (db^1)*1024 + ((n*4 + q)*8 + wv)*2) = f2bf(hn);

    if (wv == 7 && s >= 1) do_att(bh, (s^1) & 1);   // wgt(s-1) -> opposite buffer

    __syncthreads();
  }

  // ---- epilogue: last two softmax terms ----
  { const float w = ((const float*)(lds + OFF_WGT))[n];        // wgt(510) in buf 0
    accv = fmaf(w, hm2, accv); lsum += w; }
  __syncthreads();
  if (wv == 7) {
    const s16x8 bh = *(const s16x8*)(lds + OFF_HEX + (n*4 + q)*16);  // h(511) in buf 0
    do_att(bh, 1);
  }
  __syncthreads();
  { const float w = ((const float*)(lds + OFF_WGT))[16 + n];   // wgt(511)
    accv = fmaf(w, hm1, accv); lsum += w; }

  // ---- gather features: FF[n][0..31]=h_final, [32..39]=v_last fp32 ----
  ((float*)(lds + OFF_FF))[n*40 + u_own] = accv / lsum;
  if (tid < 128) ((float*)(lds + OFF_FF))[(tid >> 3)*40 + 32 + (tid & 7)] = VLAST[blk*128 + tid];
  __syncthreads();

  // ---- head MLP: wave wv handles cols 2wv, 2wv+1 ----
  const float* FF = (const float*)(lds + OFF_FF);
  float* R1 = (float*)(lds + OFF_R1);
  for (int k2 = 0; k2 < 2; ++k2) {
    const int cc = wv*2 + k2;
    if (lane < 32) {
      float a = Rb1[lane];
      for (int f = 0; f < 40; ++f) a = fmaf(FF[cc*40 + f], Rw1[f*32 + lane], a);
      R1[wv*32 + lane] = lrelu_f(a);
    }
    __syncthreads();
    float a2 = Rb2[lane];
    for (int p = 0; p < 32; ++p) a2 = fmaf(R1[wv*32 + p], Rw2[p*64 + lane], a2);
    float part = lrelu_f(a2) * Rw3[lane];
#pragma unroll
    for (int m = 1; m < 64; m <<= 1) part += __shfl_xor(part, m);
    if (lane == 0) out[blk*16 + cc] = sigf(part + Rb3[0]);
    __syncthreads();
  }
}

extern "C" void kernel_launch(void* const* d_in, const int* in_sizes, int n_in,
                              void* d_out, int out_size, void* d_ws, size_t ws_size,
                              hipStream_t stream) {
  const float* X    = (const float*)d_in[0];
  const float* We   = (const float*)d_in[1];
  const float* be   = (const float*)d_in[2];
  const float* W_ih = (const float*)d_in[3];
  const float* W_hh = (const float*)d_in[4];
  const float* b_ih = (const float*)d_in[5];
  const float* b_hh = (const float*)d_in[6];
  const float* Ew1  = (const float*)d_in[7];
  const float* Eb1  = (const float*)d_in[8];
  const float* Ew2  = (const float*)d_in[9];
  const float* Eb2  = (const float*)d_in[10];
  const float* Ew3  = (const float*)d_in[11];
  const float* Eb3  = (const float*)d_in[12];
  const float* Rw1  = (const float*)d_in[13];
  const float* Rb1  = (const float*)d_in[14];
  const float* Rw2  = (const float*)d_in[15];
  const float* Rb2  = (const float*)d_in[16];
  const float* Rw3  = (const float*)d_in[17];
  const float* Rb3  = (const float*)d_in[18];

  // workspace: V bf16 [4096][512][8] = 33,554,432 B ; VLAST fp32 [4096][8] = 131,072 B
  unsigned short* V = (unsigned short*)d_ws;
  float* VLAST = (float*)((char*)d_ws + (size_t)4096*512*8*2);

  embed_kernel<<<dim3(8192), dim3(256), 0, stream>>>(X, We, be, V, VLAST);
  arnn_kernel<<<dim3(256), dim3(512), 0, stream>>>(
      V, VLAST, W_ih, W_hh, b_ih, b_hh,
      Ew1, Eb1, Ew2, Eb2, Ew3, Eb3,
      Rw1, Rb1, Rw2, Rb2, Rw3, Rb3,
      (float*)d_out);
}

// Round 3
// 287.589 us; speedup vs baseline: 1.5191x; 1.2170x over previous
//
#include <hip/hip_runtime.h>

typedef short s16x8 __attribute__((ext_vector_type(8)));
typedef float f32x4 __attribute__((ext_vector_type(4)));
typedef unsigned int u32x4 __attribute__((ext_vector_type(4)));

#define MFMA __builtin_amdgcn_mfma_f32_16x16x32_bf16

// ---- dynamic LDS layout (bytes) ----
#define VOFF    0         // v slice: 16 rows * 512 chunks * 16B = 131072 (chunk idx XOR-swizzled)
#define OFF_HEX 131072    // h exchange: 2 dbuf * 64 chunks * 16B = 2048
#define OFF_WGT 133120    // softmax w ring: 4 slots * 16 f32 = 256
#define OFF_L1  133376    // l1 frag: 2 dbuf * 16 rows * 64B = 2048 (bf16; slots k>=16 stay zero)
#define OFF_L2  135424    // l2 frag: 2 dbuf * 16 rows * 128B = 4096 (f32 [n][32])
#define OFF_FF  139520    // final features: 16*40*4 = 2560
#define OFF_R1  142080    // head hidden: 8*32*4 = 1024
#define LDS_TOTAL 143104
#define ZERO_BYTES (OFF_FF - OFF_HEX)   // 8448 B: HEX+WGT+L1+L2

__device__ __forceinline__ short f2bf(float f) {
  union { float f; unsigned u; } v; v.f = f;
  unsigned r = v.u + 0x7fffu + ((v.u >> 16) & 1u);
  return (short)(r >> 16);
}
__device__ __forceinline__ float sigf(float x)   { return __builtin_amdgcn_rcpf(1.f + __expf(-x)); }
__device__ __forceinline__ float tanh_f(float x) { return 1.f - 2.f * __builtin_amdgcn_rcpf(__expf(2.f * x) + 1.f); }
__device__ __forceinline__ float lrelu_f(float x){ return x > 0.f ? x : 0.01f * x; }
__device__ __forceinline__ int   pk2(short a, short b){ return (int)((unsigned short)a) | ((int)((unsigned short)b) << 16); }

// ===================== kernel 1: embed v = lrelu(x@We+be) =====================
__global__ __launch_bounds__(256) void embed_kernel(
    const float* __restrict__ X, const float* __restrict__ We, const float* __restrict__ be,
    unsigned short* __restrict__ V, float* __restrict__ VLAST)
{
  __shared__ float sWe[96];
  __shared__ float sbe[8];
  const int tid = threadIdx.x;
  if (tid < 96) sWe[tid] = We[tid];
  if (tid < 8)  sbe[tid] = be[tid];
  __syncthreads();

  const long gid = (long)blockIdx.x * 256 + tid;   // gid = b*512 + s
  const float* xp = X + gid * 12;
  float xr[12];
  *(float4*)&xr[0] = *(const float4*)(xp);
  *(float4*)&xr[4] = *(const float4*)(xp + 4);
  *(float4*)&xr[8] = *(const float4*)(xp + 8);

  float v[8];
#pragma unroll
  for (int e = 0; e < 8; ++e) {
    float a = sbe[e];
#pragma unroll
    for (int i = 0; i < 12; ++i) a = fmaf(xr[i], sWe[i*8 + e], a);
    v[e] = lrelu_f(a);
  }
  unsigned int pkv[4];
#pragma unroll
  for (int d = 0; d < 4; ++d)
    pkv[d] = (unsigned)pk2(f2bf(v[2*d]), f2bf(v[2*d+1]));
  *(u32x4*)(V + gid * 8) = *(u32x4*)pkv;

  if ((gid & 511) == 511) {
    const long b = gid >> 9;
#pragma unroll
    for (int e = 0; e < 8; ++e) VLAST[b*8 + e] = v[e];
  }
}

// ===================== kernel 2: fused LSTM + pipelined attention + head =====================
__global__ __launch_bounds__(512, 1) void arnn_kernel(
    const unsigned short* __restrict__ V, const float* __restrict__ VLAST,
    const float* __restrict__ W_ih, const float* __restrict__ W_hh,
    const float* __restrict__ b_ih, const float* __restrict__ b_hh,
    const float* __restrict__ Ew1, const float* __restrict__ Eb1,
    const float* __restrict__ Ew2, const float* __restrict__ Eb2,
    const float* __restrict__ Ew3, const float* __restrict__ Eb3,
    const float* __restrict__ Rw1, const float* __restrict__ Rb1,
    const float* __restrict__ Rw2, const float* __restrict__ Rb2,
    const float* __restrict__ Rw3, const float* __restrict__ Rb3,
    float* __restrict__ out)
{
  extern __shared__ __align__(16) char lds[];
  const int tid = threadIdx.x;
  const int wv = tid >> 6;        // wave = gate M-tile index m; waves 5/6/7 also run attn stages
  const int lane = tid & 63;
  const int q = lane >> 4;
  const int n = lane & 15;        // batch column within block
  const int blk = blockIdx.x;

  // zero control LDS (HEX, WGT ring, L1, L2)
  for (int i = tid; i < ZERO_BYTES/4; i += 512) ((int*)(lds + OFF_HEX))[i] = 0;

  // ---- preload V slice into LDS (16 rows x 8KB), chunk-swizzled: lds[n][c] = v[n][c ^ (n&7)] ----
  {
    const unsigned short* vsrc = V + (long)blk*16*512*8;
#pragma unroll 2
    for (int rr = 0; rr < 16; ++rr) {
      const int cg = tid ^ (rr & 7);
      u32x4 d = *(const u32x4*)(vsrc + ((long)rr*512 + cg)*8);
      *(u32x4*)(lds + VOFF + rr*8192 + tid*16) = d;
    }
  }

  // ---- gate A-fragments: tile wv; A row r=n -> (c=n&3, u=((n>>2)&3)*8+wv); k0..31=h, k32..39=v ----
  s16x8 a0, a1;
  {
    const int c = n & 3;
    const int uu = ((n >> 2) & 3) * 8 + wv;
    const int orow = c * 32 + uu;
#pragma unroll
    for (int j = 0; j < 8; ++j) {
      a0[j] = f2bf(W_hh[orow*32 + q*8 + j]);
      a1[j] = (q == 0) ? f2bf(W_ih[orow*8 + j]) : (short)0;
    }
  }
  const int u_own = q*8 + wv;     // unit whose (i,f,g,o) this lane computes
  f32x4 biasv;
#pragma unroll
  for (int t = 0; t < 4; ++t) biasv[t] = b_ih[t*32 + u_own] + b_hh[t*32 + u_own];

  // ---- attention-stage constants ----
  s16x8 e1a0 = {}, e1a1 = {};           // wave 5 (l1)
  f32x4 eb1v = {};
  u32x4 vlf = {0,0,0,0};
  s16x8 e2t0 = {}, e2t1 = {};           // wave 6 (l2)
  f32x4 eb2a = {}, eb2b = {};
  float ew3r[8] = {0,0,0,0,0,0,0,0};    // wave 7 (l3)
  float eb3s = 0.f;
  if (wv == 5) {
#pragma unroll
    for (int j = 0; j < 8; ++j) {
      const int k = q*8 + j;
      e1a0[j] = f2bf(Ew1[k*16 + n]);                                // feat rows 0..31 = h
      e1a1[j] = (q == 0) ? f2bf(Ew1[(32 + j)*16 + n]) : (short)0;   // rows 32..39 = v_last
    }
#pragma unroll
    for (int t = 0; t < 4; ++t) eb1v[t] = Eb1[q*4 + t];
    if (q == 0) vlf = *(const u32x4*)(V + ((long)(blk*16 + n)*512 + 511)*8);
  } else if (wv == 6) {
#pragma unroll
    for (int j = 0; j < 8; ++j) {
      const int k = q*8 + j;
      e2t0[j] = (k < 16) ? f2bf(Ew2[k*32 + n])      : (short)0;
      e2t1[j] = (k < 16) ? f2bf(Ew2[k*32 + 16 + n]) : (short)0;
    }
#pragma unroll
    for (int t = 0; t < 4; ++t) { eb2a[t] = Eb2[q*4 + t]; eb2b[t] = Eb2[16 + q*4 + t]; }
  } else if (wv == 7) {
#pragma unroll
    for (int j = 0; j < 8; ++j) ew3r[j] = Ew3[q*8 + j];
    eb3s = Eb3[0];
  }

  float c_state = 0.f, accv = 0.f, lsum = 0.f;
  float hm1 = 0.f, hm2 = 0.f, hm3 = 0.f, hm4 = 0.f;
  __syncthreads();   // zeros + V preload visible

  // ---- main loop: 1 barrier/step, zero global ops ----
#pragma unroll 4
  for (int s = 0; s < 512; ++s) {
    const int p = s & 1;
    const s16x8 bh = *(const s16x8*)(lds + OFF_HEX + p*1024 + (n*4 + q)*16);        // h(s-1)
    const s16x8 bv = *(const s16x8*)(lds + VOFF + n*8192 + ((s ^ (n & 7)) << 4));   // v(s)
    const float w  = ((const float*)(lds + OFF_WGT))[((s - 4) & 3)*16 + n];         // wgt(s-4)

    f32x4 C = MFMA(a1, bv, biasv, 0, 0, 0);
    C = MFMA(a0, bh, C, 0, 0, 0);

    accv = fmaf(w, hm4, accv); lsum += w;

    const float cn = sigf(C[1])*c_state + sigf(C[0])*tanh_f(C[2]);
    const float hn = sigf(C[3])*tanh_f(cn);
    c_state = cn;
    hm4 = hm3; hm3 = hm2; hm2 = hm1; hm1 = hn;
    *(short*)(lds + OFF_HEX + (p^1)*1024 + ((n*4 + q)*8 + wv)*2) = f2bf(hn);

    if (wv == 5 && s >= 1) {            // l1(s-1): uses bh = h(s-1) already in regs
      f32x4 C1 = MFMA(e1a0, bh, eb1v, 0, 0, 0);
      C1 = MFMA(e1a1, *(const s16x8*)&vlf, C1, 0, 0, 0);
      int2 pkd;
      pkd.x = pk2(f2bf(lrelu_f(C1[0])), f2bf(lrelu_f(C1[1])));
      pkd.y = pk2(f2bf(lrelu_f(C1[2])), f2bf(lrelu_f(C1[3])));
      *(int2*)(lds + OFF_L1 + p*1024 + n*64 + q*8) = pkd;     // dims q*4+t at [n][k]
    } else if (wv == 6 && s >= 2) {     // l2(s-2): reads l1 frag from prev iter
      const s16x8 bl = *(const s16x8*)(lds + OFF_L1 + (p^1)*1024 + n*64 + q*16);
      f32x4 C2a = MFMA(e2t0, bl, eb2a, 0, 0, 0);
      f32x4 C2b = MFMA(e2t1, bl, eb2b, 0, 0, 0);
      f32x4 o1, o2;
#pragma unroll
      for (int t = 0; t < 4; ++t) { o1[t] = lrelu_f(C2a[t]); o2[t] = lrelu_f(C2b[t]); }
      *(f32x4*)(lds + OFF_L2 + p*2048 + n*128 + q*16)      = o1;   // dims q*4+t
      *(f32x4*)(lds + OFF_L2 + p*2048 + n*128 + 64 + q*16) = o2;   // dims 16+q*4+t
    } else if (wv == 7 && s >= 3) {     // l3 -> w(s-3)
      const f32x4 xa = *(const f32x4*)(lds + OFF_L2 + (p^1)*2048 + n*128 + q*32);
      const f32x4 xb = *(const f32x4*)(lds + OFF_L2 + (p^1)*2048 + n*128 + q*32 + 16);
      float part = xa[0]*ew3r[0] + xa[1]*ew3r[1] + xa[2]*ew3r[2] + xa[3]*ew3r[3]
                 + xb[0]*ew3r[4] + xb[1]*ew3r[5] + xb[2]*ew3r[6] + xb[3]*ew3r[7];
      part += __shfl_xor(part, 16);
      part += __shfl_xor(part, 32);
      const float wgt = __expf(tanh_f(part + eb3s));   // logit in [-1,1]: exp safe
      if (lane < 16) ((float*)(lds + OFF_WGT))[((s - 3) & 3)*16 + lane] = wgt;
    }
    __syncthreads();
  }

  // ---- pipeline flush: s = 512..515 (attn stages + last 4 weight accumulations) ----
  for (int s = 512; s < 516; ++s) {
    const int p = s & 1;
    const float w = ((const float*)(lds + OFF_WGT))[((s - 4) & 3)*16 + n];
    accv = fmaf(w, hm4, accv); lsum += w;
    hm4 = hm3; hm3 = hm2; hm2 = hm1;

    if (wv == 5 && s == 512) {          // l1(511)
      const s16x8 bh = *(const s16x8*)(lds + OFF_HEX + p*1024 + (n*4 + q)*16);
      f32x4 C1 = MFMA(e1a0, bh, eb1v, 0, 0, 0);
      C1 = MFMA(e1a1, *(const s16x8*)&vlf, C1, 0, 0, 0);
      int2 pkd;
      pkd.x = pk2(f2bf(lrelu_f(C1[0])), f2bf(lrelu_f(C1[1])));
      pkd.y = pk2(f2bf(lrelu_f(C1[2])), f2bf(lrelu_f(C1[3])));
      *(int2*)(lds + OFF_L1 + p*1024 + n*64 + q*8) = pkd;
    } else if (wv == 6 && s <= 513) {   // l2(510), l2(511)
      const s16x8 bl = *(const s16x8*)(lds + OFF_L1 + (p^1)*1024 + n*64 + q*16);
      f32x4 C2a = MFMA(e2t0, bl, eb2a, 0, 0, 0);
      f32x4 C2b = MFMA(e2t1, bl, eb2b, 0, 0, 0);
      f32x4 o1, o2;
#pragma unroll
      for (int t = 0; t < 4; ++t) { o1[t] = lrelu_f(C2a[t]); o2[t] = lrelu_f(C2b[t]); }
      *(f32x4*)(lds + OFF_L2 + p*2048 + n*128 + q*16)      = o1;
      *(f32x4*)(lds + OFF_L2 + p*2048 + n*128 + 64 + q*16) = o2;
    } else if (wv == 7 && s <= 514) {   // w(509), w(510), w(511)
      const f32x4 xa = *(const f32x4*)(lds + OFF_L2 + (p^1)*2048 + n*128 + q*32);
      const f32x4 xb = *(const f32x4*)(lds + OFF_L2 + (p^1)*2048 + n*128 + q*32 + 16);
      float part = xa[0]*ew3r[0] + xa[1]*ew3r[1] + xa[2]*ew3r[2] + xa[3]*ew3r[3]
                 + xb[0]*ew3r[4] + xb[1]*ew3r[5] + xb[2]*ew3r[6] + xb[3]*ew3r[7];
      part += __shfl_xor(part, 16);
      part += __shfl_xor(part, 32);
      const float wgt = __expf(tanh_f(part + eb3s));
      if (lane < 16) ((float*)(lds + OFF_WGT))[((s - 3) & 3)*16 + lane] = wgt;
    }
    __syncthreads();
  }

  // ---- gather features: FF[n][0..31]=h_final, [32..39]=v_last fp32 ----
  ((float*)(lds + OFF_FF))[n*40 + u_own] = accv / lsum;
  if (tid < 128) ((float*)(lds + OFF_FF))[(tid >> 3)*40 + 32 + (tid & 7)] = VLAST[blk*128 + tid];
  __syncthreads();

  // ---- head MLP: wave wv handles batch cols 2wv, 2wv+1 ----
  const float* FF = (const float*)(lds + OFF_FF);
  float* R1 = (float*)(lds + OFF_R1);
  for (int k2 = 0; k2 < 2; ++k2) {
    const int cc = wv*2 + k2;
    if (lane < 32) {
      float a = Rb1[lane];
      for (int f = 0; f < 40; ++f) a = fmaf(FF[cc*40 + f], Rw1[f*32 + lane], a);
      R1[wv*32 + lane] = lrelu_f(a);
    }
    __syncthreads();
    float a2 = Rb2[lane];
    for (int p2 = 0; p2 < 32; ++p2) a2 = fmaf(R1[wv*32 + p2], Rw2[p2*64 + lane], a2);
    float part = lrelu_f(a2) * Rw3[lane];
#pragma unroll
    for (int m = 1; m < 64; m <<= 1) part += __shfl_xor(part, m);
    if (lane == 0) out[blk*16 + cc] = sigf(part + Rb3[0]);
    __syncthreads();
  }
}

extern "C" void kernel_launch(void* const* d_in, const int* in_sizes, int n_in,
                              void* d_out, int out_size, void* d_ws, size_t ws_size,
                              hipStream_t stream) {
  const float* X    = (const float*)d_in[0];
  const float* We   = (const float*)d_in[1];
  const float* be   = (const float*)d_in[2];
  const float* W_ih = (const float*)d_in[3];
  const float* W_hh = (const float*)d_in[4];
  const float* b_ih = (const float*)d_in[5];
  const float* b_hh = (const float*)d_in[6];
  const float* Ew1  = (const float*)d_in[7];
  const float* Eb1  = (const float*)d_in[8];
  const float* Ew2  = (const float*)d_in[9];
  const float* Eb2  = (const float*)d_in[10];
  const float* Ew3  = (const float*)d_in[11];
  const float* Eb3  = (const float*)d_in[12];
  const float* Rw1  = (const float*)d_in[13];
  const float* Rb1  = (const float*)d_in[14];
  const float* Rw2  = (const float*)d_in[15];
  const float* Rb2  = (const float*)d_in[16];
  const float* Rw3  = (const float*)d_in[17];
  const float* Rb3  = (const float*)d_in[18];

  // workspace: V bf16 [4096][512][8] = 33,554,432 B ; VLAST fp32 [4096][8] = 131,072 B
  unsigned short* V = (unsigned short*)d_ws;
  float* VLAST = (float*)((char*)d_ws + (size_t)4096*512*8*2);

  hipFuncSetAttribute(reinterpret_cast<const void*>(arnn_kernel),
                      hipFuncAttributeMaxDynamicSharedMemorySize, LDS_TOTAL);

  embed_kernel<<<dim3(8192), dim3(256), 0, stream>>>(X, We, be, V, VLAST);
  arnn_kernel<<<dim3(256), dim3(512), LDS_TOTAL, stream>>>(
      V, VLAST, W_ih, W_hh, b_ih, b_hh,
      Ew1, Eb1, Ew2, Eb2, Ew3, Eb3,
      Rw1, Rb1, Rw2, Rb2, Rw3, Rb3,
      (float*)d_out);
}